// Round 11
// baseline (592.201 us; speedup 1.0000x reference)
//
#include <hip/hip_runtime.h>
#include <hip/hip_bf16.h>

#define N_NODES 50000
#define N_EDGES 800000
#define NC 16
#define FDIM 13
#define HID 32
#define RT_ROW 528     // 16 outputs * 32 hidden + 16 b2-terms (bf16)
#define EPB 64         // edges per msg tile

// big-ws path: padded-bucket sort (no scan, no separate scatter)
#define BSH 3          // bucket = 8 nodes, lambda = 128 edges
#define NBUCK 6250
#define CAP 192        // lambda + ~5.7 sigma; spill list covers the tail
#define TPB 3          // tiles per bucket = CAP/EPB
#define NTILES (NBUCK * TPB)   // 18750
#define OVB 2
#define OVCAP 4096

// fallback path (R9-proven): exact counting sort
#define NBUCK9 6400
#define MTILE 12500

typedef unsigned short ushort_t;
typedef unsigned int uint_t;
typedef __attribute__((ext_vector_type(8))) unsigned short u16x8;

__device__ __forceinline__ float bf2f(ushort_t u) {
  union { unsigned int i; float f; } v; v.i = ((unsigned int)u) << 16; return v.f;
}
__device__ __forceinline__ ushort_t f2bf(float f) {
  union { unsigned int i; float f; } v; v.f = f;
  unsigned int r = v.i + 0x7FFFu + ((v.i >> 16) & 1u);   // RNE
  return (ushort_t)(r >> 16);
}
// unpack a bf16 pair (lo = low 16 bits, hi = high 16 bits)
__device__ __forceinline__ float pklo(uint_t p) {
  union { uint_t i; float f; } v; v.i = p << 16; return v.f;
}
__device__ __forceinline__ float pkhi(uint_t p) {
  union { uint_t i; float f; } v; v.i = p & 0xFFFF0000u; return v.f;
}
__device__ __forceinline__ float loadf(const void* p, int i, int isf32) {
  return isf32 ? ((const float*)p)[i] : bf2f(((const ushort_t*)p)[i]);
}
__device__ __forceinline__ float sigmoidf_(float x) { return 1.0f / (1.0f + __expf(-x)); }
__device__ __forceinline__ float tanhf_(float x) { return 1.0f - 2.0f / (__expf(2.0f * x) + 1.0f); }

// packed bf16 pair dot-accumulate (R9-proven)
__device__ __forceinline__ float dot2bf(uint_t a, uint_t b, float c) {
  float d;
  asm("v_dot2_f32_bf16 %0, %1, %2, %3" : "=v"(d) : "v"(a), "v"(b), "v"(c));
  return d;
}

// ballot-based dtype detect (1 = fp32 inputs)
__device__ __forceinline__ int detect_f32(const void* hx_in) {
  __shared__ int wc[4];
  int tid = threadIdx.x;
  uint_t lo = ((const uint_t*)hx_in)[tid] & 0xFFFFu;
  uint_t ex = (lo >> 7) & 0xFFu;
  int wild = (ex < 103u || ex > 151u) && lo != 0u && lo != 0x8000u;
  unsigned long long m = __ballot(wild);
  if ((tid & 63) == 0) wc[tid >> 6] = __popcll(m);
  __syncthreads();
  int c = wc[0] + wc[1] + wc[2] + wc[3];
  __syncthreads();
  return c > 64;
}

// stage w2 as bf16 pairs over h: w2p[io*18 + hp] = pack(w2[2hp][io], w2[2hp+1][io])
// 18.4 KB (was 36.9 fp32) -> ~2x blocks/CU. Stage writes: lane stride 18 -> 4-way.
__device__ __forceinline__ void stage_w2p(const void* w2, const void* b2,
                                          uint_t* w2p, float* b2s, int isf32) {
  int tid = threadIdx.x;
  for (int k = tid; k < 256 * 16; k += 256) {
    int io = k & 255, hp = k >> 8;
    float f0 = loadf(w2, (2 * hp) * 256 + io, isf32);
    float f1 = loadf(w2, (2 * hp + 1) * 256 + io, isf32);
    w2p[io * 18 + hp] = (uint_t)f2bf(f0) | ((uint_t)f2bf(f1) << 16);
  }
  b2s[tid] = loadf(b2, tid, isf32);
}

// Rt row build from packed w2: lane owns output o; stride-18 uint4 reads are
// 16B-aligned (72 B row stride) and 2-way-bank at worst (free).
__device__ __forceinline__ void rt_row_p(const float* hxr, const uint_t* w2p,
                                         const float* b2s, ushort_t* rowp, int o) {
  #pragma unroll
  for (int c = 0; c < 4; c++) {
    float a8[8] = {0, 0, 0, 0, 0, 0, 0, 0};
    #pragma unroll
    for (int i = 0; i < 16; i++) {
      uint4 wv = *(const uint4*)&w2p[(i * 16 + o) * 18 + c * 4];
      float hv = hxr[i];
      a8[0] += hv * pklo(wv.x); a8[1] += hv * pkhi(wv.x);
      a8[2] += hv * pklo(wv.y); a8[3] += hv * pkhi(wv.y);
      a8[4] += hv * pklo(wv.z); a8[5] += hv * pkhi(wv.z);
      a8[6] += hv * pklo(wv.w); a8[7] += hv * pkhi(wv.w);
    }
    u16x8 ov;
    #pragma unroll
    for (int j = 0; j < 8; j++) ov[j] = f2bf(a8[j]);
    *(u16x8*)(rowp + o * 32 + c * 8) = ov;
  }
  float vb = 0.0f;
  #pragma unroll
  for (int i = 0; i < 16; i++) vb += hxr[i] * b2s[i * 16 + o];
  rowp[512 + o] = f2bf(vb);
}

// ============ BIG PATH ============
// kernel 1: loads-only before the barrier (minimal vmcnt drain); all scattered
// writes/atomics after it. LDS ~22.5 KB -> ~7 blocks/CU.
__global__ void __launch_bounds__(256) k_pre_big(
    const void* __restrict__ hx_in, const void* __restrict__ ef,
    const int* __restrict__ src, const int* __restrict__ dst,
    const void* __restrict__ w1, const void* __restrict__ b1,
    const void* __restrict__ w2, const void* __restrict__ b2,
    float* __restrict__ hx32, float* __restrict__ agg, float* __restrict__ deg,
    int* __restrict__ cnt, int* __restrict__ ovfcnt, int* __restrict__ ovf,
    uint2* __restrict__ sortbuf, ushort_t* __restrict__ hidden,
    ushort_t* __restrict__ Rt) {
  __shared__ float w1s[FDIM * HID];
  __shared__ float b1s[HID];
  __shared__ uint_t w2p[256 * 18];
  __shared__ float b2s[256];
  __shared__ float hx_l[16 * 17];
  int tid = threadIdx.x;
  int isf32 = detect_f32(hx_in);
  for (int k = tid; k < FDIM * HID; k += 256) w1s[k] = loadf(w1, k, isf32);
  if (tid < HID) b1s[tid] = loadf(b1, tid, isf32);
  stage_w2p(w2, b2, w2p, b2s, isf32);

  int idx = blockIdx.x * 256 + tid;            // grid 3125 covers E == N*NC
  int vl = tid >> 4, o = tid & 15;
  float hv = loadf(hx_in, idx, isf32);
  hx_l[vl * 17 + o] = hv;
  __syncthreads();                             // drains only the hx load

  // issue independent global loads early
  int e = idx;
  int s = src[e], d = dst[e];
  float efr[FDIM];
  #pragma unroll
  for (int i = 0; i < FDIM; i++) efr[i] = loadf(ef, e * FDIM + i, isf32);

  hx32[idx] = hv;
  agg[idx] = 0.0f;

  // Rt build (LDS + VALU, overlaps the loads above)
  float hxr[16];
  #pragma unroll
  for (int i = 0; i < 16; i++) hxr[i] = hx_l[vl * 17 + i];
  rt_row_p(hxr, w2p, b2s, Rt + (size_t)(idx >> 4) * RT_ROW, o);

  // MLP hidden, edge order (coalesced streaming)
  u16x8* hrow = (u16x8*)(hidden + (size_t)e * HID);
  #pragma unroll
  for (int c = 0; c < 4; c++) {
    u16x8 ov;
    #pragma unroll
    for (int j = 0; j < 8; j++) {
      int h = c * 8 + j;
      float acc = b1s[h];
      #pragma unroll
      for (int i = 0; i < FDIM; i++) acc += efr[i] * w1s[i * HID + h];
      ov[j] = f2bf(fmaxf(acc, 0.0f));
    }
    hrow[c] = ov;
  }

  // scatter + degree at the very end (no barrier after -> latency not shared)
  atomicAdd(&deg[d], 1.0f);
  int b = s >> BSH;
  int p = atomicAdd(&cnt[b], 1);
  if (p < CAP) {
    uint2 rec; rec.x = ((uint_t)s << 16) | (uint_t)d; rec.y = (uint_t)e;
    sortbuf[b * CAP + p] = rec;
  } else {
    int op = atomicAdd(ovfcnt, 1);
    if (op < OVCAP) ovf[op] = e;
  }
}

// kernel 2/4: per-edge message — gather 64 B hidden rows, dot2 with Rt, scatter
__global__ void __launch_bounds__(256) k_msg_big(
    const int* __restrict__ src, const int* __restrict__ dst,
    const int* __restrict__ cnt, const int* __restrict__ ovfcnt,
    const int* __restrict__ ovf, const uint2* __restrict__ sortbuf,
    const ushort_t* __restrict__ hidden, const ushort_t* __restrict__ Rt,
    float* __restrict__ agg) {
  __shared__ uint_t hsp[EPB * 20];
  __shared__ int ssrc[EPB], sdst[EPB], seid[EPB];
  int tid = threadIdx.x;
  int t = blockIdx.x;
  if (t < NTILES) {
    int b = t / TPB, ls0 = (t - b * TPB) * EPB;
    int cb = cnt[b]; if (cb > CAP) cb = CAP;
    int nv = cb - ls0; if (nv <= 0) return;
    if (nv > EPB) nv = EPB;
    if (tid < EPB) {
      uint2 rec;
      if (tid < nv) rec = sortbuf[b * CAP + ls0 + tid];
      else { rec.x = 0u; rec.y = 0u; }
      ssrc[tid] = (int)(rec.x >> 16); sdst[tid] = (int)(rec.x & 0xFFFFu);
      seid[tid] = (int)rec.y;
    }
    __syncthreads();
    {
      int row = tid >> 2, chunk = tid & 3;
      uint4 hv = ((const uint4*)(hidden + (size_t)seid[row] * HID))[chunk];
      int base = row * 20 + chunk * 4;
      hsp[base] = hv.x; hsp[base + 1] = hv.y; hsp[base + 2] = hv.z; hsp[base + 3] = hv.w;
    }
    __syncthreads();
    #pragma unroll
    for (int q = 0; q < 4; q++) {
      int item = q * 256 + tid, le = item >> 4, o = item & 15;
      if (le < nv) {
        int s = ssrc[le], d = sdst[le];
        const ushort_t* rrow = Rt + (size_t)s * RT_ROW;
        const uint_t* ru = (const uint_t*)(rrow + o * 32);
        const uint_t* hp = &hsp[le * 20];
        float acc = bf2f(rrow[512 + o]);
        #pragma unroll
        for (int k = 0; k < 16; k++) acc = dot2bf(hp[k], ru[k], acc);
        atomicAdd(&agg[d * NC + o], acc);
      }
    }
  } else {
    int on = *ovfcnt; if (on > OVCAP) on = OVCAP;
    for (int i = (t - NTILES) * 256 + tid; i < on * NC; i += OVB * 256) {
      int e = ovf[i >> 4], o = i & 15;
      int s = src[e], d = dst[e];
      const ushort_t* rrow = Rt + (size_t)s * RT_ROW;
      const uint_t* ru = (const uint_t*)(rrow + o * 32);
      const uint_t* hp = (const uint_t*)(hidden + (size_t)e * HID);
      float acc = bf2f(rrow[512 + o]);
      for (int k = 0; k < 16; k++) acc = dot2bf(hp[k], ru[k], acc);
      atomicAdd(&agg[d * NC + o], acc);
    }
  }
}

// ============ GRU ============
__device__ __forceinline__ void stage_gru(const void* w_ih, const void* w_hh,
                                          const void* b_ih, const void* b_hh,
                                          float* wihT, float* whhT,
                                          float* bih, float* bhh, int isf32, int tid) {
  for (int kk = tid; kk < 3 * NC * NC; kk += 256) {
    int g = kk >> 8, rem = kk & 255, o = rem >> 4, k = rem & 15;
    wihT[g * 272 + k * 17 + o] = loadf(w_ih, kk, isf32);
    whhT[g * 272 + k * 17 + o] = loadf(w_hh, kk, isf32);
  }
  if (tid < 3 * NC) { bih[tid] = loadf(b_ih, tid, isf32); bhh[tid] = loadf(b_hh, tid, isf32); }
}
__device__ __forceinline__ float gru_core(const float* wihT, const float* whhT,
                                          const float* bih, const float* bhh,
                                          const float* x, const float* h, int o) {
  float gir = bih[o], giz = bih[NC + o], gin = bih[2 * NC + o];
  float ghr = bhh[o], ghz = bhh[NC + o], ghn = bhh[2 * NC + o];
  #pragma unroll
  for (int k = 0; k < NC; k++) {
    gir += x[k] * wihT[k * 17 + o];
    giz += x[k] * wihT[272 + k * 17 + o];
    gin += x[k] * wihT[544 + k * 17 + o];
    ghr += h[k] * whhT[k * 17 + o];
    ghz += h[k] * whhT[272 + k * 17 + o];
    ghn += h[k] * whhT[544 + k * 17 + o];
  }
  float r = sigmoidf_(gir + ghr);
  float z = sigmoidf_(giz + ghz);
  float n = tanhf_(gin + r * ghn);
  return (1.0f - z) * n + z * h[o];
}
__device__ __forceinline__ void load_xh(const float* agg, const float* hx, int v,
                                        float inv, float* x, float* h) {
  const float4* ar = (const float4*)(agg + v * NC);
  const float4* hr = (const float4*)(hx + v * NC);
  #pragma unroll
  for (int q = 0; q < 4; q++) {
    float4 aa = ar[q], bb = hr[q];
    x[4 * q + 0] = aa.x * inv; x[4 * q + 1] = aa.y * inv; x[4 * q + 2] = aa.z * inv; x[4 * q + 3] = aa.w * inv;
    h[4 * q + 0] = bb.x; h[4 * q + 1] = bb.y; h[4 * q + 2] = bb.z; h[4 * q + 3] = bb.w;
  }
}

// kernel 3: GRU update (in place) + Rt rebuild + agg re-zero
__global__ void __launch_bounds__(256) k_update(
    const void* __restrict__ hx_in, const float* __restrict__ agg_in,
    const float* __restrict__ deg, float* __restrict__ hx,
    const void* __restrict__ w_ih, const void* __restrict__ w_hh,
    const void* __restrict__ b_ih, const void* __restrict__ b_hh,
    const void* __restrict__ w2, const void* __restrict__ b2,
    ushort_t* __restrict__ Rt, float* __restrict__ agg_out) {
  __shared__ uint_t w2p[256 * 18];
  __shared__ float b2s[256];
  __shared__ float wihT[816], whhT[816], bih[48], bhh[48];
  __shared__ float hx_l[16 * 17];
  int tid = threadIdx.x;
  int isf32 = detect_f32(hx_in);
  stage_w2p(w2, b2, w2p, b2s, isf32);
  stage_gru(w_ih, w_hh, b_ih, b_hh, wihT, whhT, bih, bhh, isf32, tid);
  __syncthreads();

  int idx = blockIdx.x * 256 + tid;
  int v = idx >> 4, o = idx & 15, vl = tid >> 4;
  float inv = 1.0f / fmaxf(deg[v], 1.0f);
  float x[16], h[16];
  load_xh(agg_in, hx, v, inv, x, h);
  float hn = gru_core(wihT, whhT, bih, bhh, x, h, o);
  hx_l[vl * 17 + o] = hn;
  __syncthreads();                 // hx row fully read+staged before in-place write
  hx[idx] = hn;
  agg_out[idx] = 0.0f;

  float hxr[16];
  #pragma unroll
  for (int i = 0; i < 16; i++) hxr[i] = hx_l[vl * 17 + i];
  rt_row_p(hxr, w2p, b2s, Rt + (size_t)v * RT_ROW, o);
}

// kernel 5: final GRU -> d_out
__global__ void __launch_bounds__(256) k_gru(
    const void* __restrict__ hx_in, const float* __restrict__ agg,
    const float* __restrict__ deg, const float* __restrict__ hx,
    const void* __restrict__ w_ih, const void* __restrict__ w_hh,
    const void* __restrict__ b_ih, const void* __restrict__ b_hh,
    void* __restrict__ out) {
  __shared__ float wihT[816], whhT[816], bih[48], bhh[48];
  int tid = threadIdx.x;
  int isf32 = detect_f32(hx_in);
  stage_gru(w_ih, w_hh, b_ih, b_hh, wihT, whhT, bih, bhh, isf32, tid);
  __syncthreads();
  int idx = blockIdx.x * 256 + tid;
  int v = idx >> 4, o = idx & 15;
  float inv = 1.0f / fmaxf(deg[v], 1.0f);
  float x[16], h[16];
  load_xh(agg, hx, v, inv, x, h);
  float hn = gru_core(wihT, whhT, bih, bhh, x, h, o);
  if (isf32) ((float*)out)[idx] = hn;
  else       ((ushort_t*)out)[idx] = f2bf(hn);
}

// ============ FALLBACK PATH (small ws; R9 lineage, packed w2) ============
__global__ void k_pre9(const void* __restrict__ hx_in, float* __restrict__ hx32,
                       const int* __restrict__ src, const int* __restrict__ dst,
                       float* __restrict__ deg, int* __restrict__ hist) {
  int isf32 = detect_f32(hx_in);
  int idx = blockIdx.x * 256 + threadIdx.x;
  hx32[idx] = loadf(hx_in, idx, isf32);
  atomicAdd(&deg[dst[idx]], 1.0f);
  atomicAdd(&hist[src[idx] >> BSH], 1);
}

__global__ void k_scan_rnode9(const void* __restrict__ hx_in, int* __restrict__ hist,
                              const float* __restrict__ hx, const void* __restrict__ w2,
                              const void* __restrict__ b2, ushort_t* __restrict__ Rt,
                              float* __restrict__ agg) {
  __shared__ int lds[NBUCK9];
  __shared__ int psum[256];
  __shared__ uint_t w2p[256 * 18];
  __shared__ float b2s[256];
  int tid = threadIdx.x;
  if (blockIdx.x == 0) {
    for (int i = tid; i < NBUCK9; i += 256) lds[i] = hist[i];
    __syncthreads();
    int base = tid * 25, s = 0;
    #pragma unroll
    for (int i = 0; i < 25; i++) { int v = lds[base + i]; lds[base + i] = s; s += v; }
    psum[tid] = s;
    __syncthreads();
    if (tid == 0) { int run = 0; for (int i = 0; i < 256; i++) { int v = psum[i]; psum[i] = run; run += v; } }
    __syncthreads();
    int off = psum[tid];
    #pragma unroll
    for (int i = 0; i < 25; i++) lds[base + i] += off;
    __syncthreads();
    for (int i = tid; i < NBUCK9; i += 256) hist[i] = lds[i];
    return;
  }
  int isf32 = detect_f32(hx_in);
  stage_w2p(w2, b2, w2p, b2s, isf32);
  __syncthreads();
  int idx = (blockIdx.x - 1) * 256 + tid;
  agg[idx] = 0.0f;
  int node = idx >> 4, o = idx & 15;
  float hxr[16];
  const float4* hp = (const float4*)(hx + node * NC);
  #pragma unroll
  for (int q = 0; q < 4; q++) {
    float4 t = hp[q];
    hxr[4 * q + 0] = t.x; hxr[4 * q + 1] = t.y; hxr[4 * q + 2] = t.z; hxr[4 * q + 3] = t.w;
  }
  rt_row_p(hxr, w2p, b2s, Rt + (size_t)node * RT_ROW, o);
}

__global__ void k_scatter9(const int* __restrict__ src, const int* __restrict__ dst,
                           int* __restrict__ cursors, uint2* __restrict__ sortbuf) {
  int e = blockIdx.x * 256 + threadIdx.x;
  int s = src[e];
  int p = atomicAdd(&cursors[s >> BSH], 1);
  uint2 rec; rec.x = ((uint_t)s << 16) | (uint_t)dst[e]; rec.y = (uint_t)e;
  sortbuf[p] = rec;
}

__global__ void __launch_bounds__(256) k_msg9(
    const void* __restrict__ hx_in, const uint2* __restrict__ sortbuf,
    const void* __restrict__ ef, const void* __restrict__ w1,
    const void* __restrict__ b1, const ushort_t* __restrict__ Rt,
    float* __restrict__ agg) {
  __shared__ float w1s[FDIM * HID];
  __shared__ float b1s[HID];
  __shared__ float efs[EPB * FDIM];
  __shared__ uint_t hsp[EPB * 20];
  __shared__ int ssrc[EPB], sdst[EPB], seid[EPB];
  int tid = threadIdx.x;
  int isf32 = detect_f32(hx_in);
  int e0 = blockIdx.x * EPB;
  for (int k = tid; k < FDIM * HID; k += 256) w1s[k] = loadf(w1, k, isf32);
  if (tid < HID) b1s[tid] = loadf(b1, tid, isf32);
  if (tid < EPB) {
    uint2 rec = sortbuf[e0 + tid];
    ssrc[tid] = (int)(rec.x >> 16); sdst[tid] = (int)(rec.x & 0xFFFFu);
    seid[tid] = (int)rec.y;
  }
  __syncthreads();
  #pragma unroll
  for (int q = 0; q < 4; q++) {
    int j = q * 256 + tid, le = j >> 4, i = j & 15;
    if (i < FDIM) efs[le * FDIM + i] = loadf(ef, seid[le] * FDIM + i, isf32);
  }
  __syncthreads();
  #pragma unroll
  for (int q = 0; q < 4; q++) {
    int v = q * 256 + tid;
    int le = v >> 4, hp2 = v & 15, h0 = hp2 * 2;
    float a0 = b1s[h0], a1 = b1s[h0 + 1];
    #pragma unroll
    for (int i = 0; i < FDIM; i++) {
      float e = efs[le * FDIM + i];
      a0 += e * w1s[i * HID + h0];
      a1 += e * w1s[i * HID + h0 + 1];
    }
    hsp[le * 20 + hp2] = (uint_t)f2bf(fmaxf(a0, 0.0f)) | ((uint_t)f2bf(fmaxf(a1, 0.0f)) << 16);
  }
  __syncthreads();
  #pragma unroll
  for (int q = 0; q < 4; q++) {
    int item = q * 256 + tid, le = item >> 4, o = item & 15;
    int s = ssrc[le], d = sdst[le];
    const ushort_t* rrow = Rt + (size_t)s * RT_ROW;
    const uint_t* ru = (const uint_t*)(rrow + o * 32);
    const uint_t* hp = &hsp[le * 20];
    float acc = bf2f(rrow[512 + o]);
    #pragma unroll
    for (int k = 0; k < 16; k++) acc = dot2bf(hp[k], ru[k], acc);
    atomicAdd(&agg[d * NC + o], acc);
  }
}

extern "C" void kernel_launch(void* const* d_in, const int* in_sizes, int n_in,
                              void* d_out, int out_size, void* d_ws, size_t ws_size,
                              hipStream_t stream) {
  const void* hx_in = d_in[0];
  const void* ef    = d_in[1];
  const int*  esrc  = (const int*)d_in[2];
  const int*  edst  = (const int*)d_in[3];
  const void* w1    = d_in[4];
  const void* b1    = d_in[5];
  const void* w2    = d_in[6];
  const void* b2    = d_in[7];
  const void* wih   = d_in[8];
  const void* whh   = d_in[9];
  const void* bih_g = d_in[10];
  const void* bhh_g = d_in[11];

  char* ws = (char*)d_ws;
  float* hx32   = (float*)(ws + 0);          //  3,200,000
  float* agg    = (float*)(ws + 3200000);    //  3,200,000
  float* deg    = (float*)(ws + 6400000);    //    200,000  -- zero region start
  int*   cnt    = (int*)  (ws + 6600000);    //     25,600
  int*   ovfcnt = (int*)  (ws + 6625600);    //         32  -- zero region end
  int*   ovf    = (int*)  (ws + 6625632);    //     16,384
  uint2*    sortbufB = (uint2*)(ws + 6642016);       //  9,600,000
  ushort_t* hiddenB  = (ushort_t*)(ws + 16242016);   // 51,200,000
  ushort_t* RtB      = (ushort_t*)(ws + 67442016);   // 52,800,000 -> 120,242,016
  uint2*    sortbuf9 = (uint2*)(ws + 6642016);       //  6,400,000
  ushort_t* Rt9      = (ushort_t*)(ws + 13042016);   // 52,800,000 -> 65,842,016

  int big = (ws_size >= (size_t)120242016);
  hipMemsetAsync(ws + 6400000, 0, 225632, stream);   // deg + cnt + ovfcnt

  if (big) {
    k_pre_big<<<3125, 256, 0, stream>>>(hx_in, ef, esrc, edst, w1, b1, w2, b2,
                                        hx32, agg, deg, cnt, ovfcnt, ovf,
                                        sortbufB, hiddenB, RtB);
    k_msg_big<<<NTILES + OVB, 256, 0, stream>>>(esrc, edst, cnt, ovfcnt, ovf,
                                                sortbufB, hiddenB, RtB, agg);
    k_update<<<3125, 256, 0, stream>>>(hx_in, agg, deg, hx32, wih, whh, bih_g, bhh_g,
                                       w2, b2, RtB, agg);
    k_msg_big<<<NTILES + OVB, 256, 0, stream>>>(esrc, edst, cnt, ovfcnt, ovf,
                                                sortbufB, hiddenB, RtB, agg);
    k_gru<<<3125, 256, 0, stream>>>(hx_in, agg, deg, hx32, wih, whh, bih_g, bhh_g, d_out);
  } else {
    k_pre9<<<3125, 256, 0, stream>>>(hx_in, hx32, esrc, edst, deg, cnt);
    k_scan_rnode9<<<3126, 256, 0, stream>>>(hx_in, cnt, hx32, w2, b2, Rt9, agg);
    k_scatter9<<<3125, 256, 0, stream>>>(esrc, edst, cnt, sortbuf9);
    k_msg9<<<MTILE, 256, 0, stream>>>(hx_in, sortbuf9, ef, w1, b1, Rt9, agg);
    k_update<<<3125, 256, 0, stream>>>(hx_in, agg, deg, hx32, wih, whh, bih_g, bhh_g,
                                       w2, b2, Rt9, agg);
    k_msg9<<<MTILE, 256, 0, stream>>>(hx_in, sortbuf9, ef, w1, b1, Rt9, agg);
    k_gru<<<3125, 256, 0, stream>>>(hx_in, agg, deg, hx32, wih, whh, bih_g, bhh_g, d_out);
  }
}

// Round 12
// 441.123 us; speedup vs baseline: 1.3425x; 1.3425x over previous
//
#include <hip/hip_runtime.h>
#include <hip/hip_bf16.h>

#define N_NODES 50000
#define N_EDGES 800000
#define NC 16
#define FDIM 13
#define HID 32
#define RT_ROW 528     // 16 outputs * 32 hidden + 16 b2-terms (bf16)
#define EPB 64         // edges per msg tile

// big-ws path: padded-bucket sort
#define BSH 3          // bucket = 8 nodes, lambda = 128 edges
#define NBUCK 6250
#define CAP 192
#define TPB 3
#define NTILES (NBUCK * TPB)   // 18750
#define OVB 2
#define OVCAP 4096

// fallback path (R9-proven): exact counting sort
#define NBUCK9 6400
#define MTILE 12500

typedef unsigned short ushort_t;
typedef unsigned int uint_t;
typedef __attribute__((ext_vector_type(8))) unsigned short u16x8;

__device__ __forceinline__ float bf2f(ushort_t u) {
  union { unsigned int i; float f; } v; v.i = ((unsigned int)u) << 16; return v.f;
}
__device__ __forceinline__ ushort_t f2bf(float f) {
  union { unsigned int i; float f; } v; v.f = f;
  unsigned int r = v.i + 0x7FFFu + ((v.i >> 16) & 1u);   // RNE
  return (ushort_t)(r >> 16);
}
__device__ __forceinline__ float loadf(const void* p, int i, int isf32) {
  return isf32 ? ((const float*)p)[i] : bf2f(((const ushort_t*)p)[i]);
}
__device__ __forceinline__ float sigmoidf_(float x) { return 1.0f / (1.0f + __expf(-x)); }
__device__ __forceinline__ float tanhf_(float x) { return 1.0f - 2.0f / (__expf(2.0f * x) + 1.0f); }

// packed bf16 pair dot-accumulate (R9-proven)
__device__ __forceinline__ float dot2bf(uint_t a, uint_t b, float c) {
  float d;
  asm("v_dot2_f32_bf16 %0, %1, %2, %3" : "=v"(d) : "v"(a), "v"(b), "v"(c));
  return d;
}

// ballot-based dtype detect (1 = fp32 inputs)
__device__ __forceinline__ int detect_f32(const void* hx_in) {
  __shared__ int wc[4];
  int tid = threadIdx.x;
  uint_t lo = ((const uint_t*)hx_in)[tid] & 0xFFFFu;
  uint_t ex = (lo >> 7) & 0xFFu;
  int wild = (ex < 103u || ex > 151u) && lo != 0u && lo != 0x8000u;
  unsigned long long m = __ballot(wild);
  if ((tid & 63) == 0) wc[tid >> 6] = __popcll(m);
  __syncthreads();
  int c = wc[0] + wc[1] + wc[2] + wc[3];
  __syncthreads();
  return c > 64;
}

__device__ __forceinline__ void stage_w2(const void* w2, const void* b2,
                                         float* w2t, float* b2s, int isf32) {
  int tid = threadIdx.x;
  for (int k = tid; k < 256 * HID; k += 256) {
    int h = k >> 8, io = k & 255;
    w2t[io * 36 + h] = loadf(w2, h * 256 + io, isf32);
  }
  b2s[tid] = loadf(b2, tid, isf32);
}

// Rt row build: lane owns output o; hxr[16] = node row; w2t [io][h] stride 36
__device__ __forceinline__ void rt_row(const float* hxr, const float* w2t,
                                       const float* b2s, ushort_t* rowp, int o) {
  #pragma unroll
  for (int c = 0; c < 4; c++) {
    float a8[8] = {0, 0, 0, 0, 0, 0, 0, 0};
    #pragma unroll
    for (int i = 0; i < 16; i++) {
      const float* wp = &w2t[(i * 16 + o) * 36 + c * 8];
      float4 wa = *(const float4*)(wp);
      float4 wb = *(const float4*)(wp + 4);
      a8[0] += hxr[i] * wa.x; a8[1] += hxr[i] * wa.y; a8[2] += hxr[i] * wa.z; a8[3] += hxr[i] * wa.w;
      a8[4] += hxr[i] * wb.x; a8[5] += hxr[i] * wb.y; a8[6] += hxr[i] * wb.z; a8[7] += hxr[i] * wb.w;
    }
    u16x8 ov;
    #pragma unroll
    for (int j = 0; j < 8; j++) ov[j] = f2bf(a8[j]);
    *(u16x8*)(rowp + o * 32 + c * 8) = ov;
  }
  float vb = 0.0f;
  #pragma unroll
  for (int i = 0; i < 16; i++) vb += hxr[i] * b2s[i * 16 + o];
  rowp[512 + o] = f2bf(vb);
}

// ============ BIG PATH ============
// kernel 1a: node-side — hx->fp32 + Rt build + agg zero (no atomics, no scatter)
__global__ void __launch_bounds__(256) k_node(
    const void* __restrict__ hx_in, const void* __restrict__ w2,
    const void* __restrict__ b2, float* __restrict__ hx32,
    float* __restrict__ agg, ushort_t* __restrict__ Rt) {
  __shared__ float w2t[256 * 36];
  __shared__ float b2s[256];
  __shared__ float hx_l[16 * 17];
  int tid = threadIdx.x;
  int isf32 = detect_f32(hx_in);
  stage_w2(w2, b2, w2t, b2s, isf32);

  int idx = blockIdx.x * 256 + tid;            // grid 3125 covers N*NC
  int vl = tid >> 4, o = tid & 15;
  float hv = loadf(hx_in, idx, isf32);
  hx32[idx] = hv;
  hx_l[vl * 17 + o] = hv;
  agg[idx] = 0.0f;
  __syncthreads();

  float hxr[16];
  #pragma unroll
  for (int i = 0; i < 16; i++) hxr[i] = hx_l[vl * 17 + i];
  rt_row(hxr, w2t, b2s, Rt + (size_t)(idx >> 4) * RT_ROW, o);
}

// kernel 1b: edge-side — MLP hidden (streaming) + deg + bucket scatter.
// Tiny LDS (~2 KB) + few live regs -> high occupancy hides atomic latency.
__global__ void __launch_bounds__(256) k_edge_pre(
    const void* __restrict__ hx_in, const void* __restrict__ ef,
    const int* __restrict__ src, const int* __restrict__ dst,
    const void* __restrict__ w1, const void* __restrict__ b1,
    float* __restrict__ deg, int* __restrict__ cnt, int* __restrict__ ovfcnt,
    int* __restrict__ ovf, uint2* __restrict__ sortbuf,
    ushort_t* __restrict__ hidden) {
  __shared__ float w1s[FDIM * HID];
  __shared__ float b1s[HID];
  int tid = threadIdx.x;
  int isf32 = detect_f32(hx_in);
  for (int k = tid; k < FDIM * HID; k += 256) w1s[k] = loadf(w1, k, isf32);
  if (tid < HID) b1s[tid] = loadf(b1, tid, isf32);
  __syncthreads();

  int e = blockIdx.x * 256 + tid;              // grid 3125 covers E
  int s = src[e], d = dst[e];
  float efr[FDIM];
  #pragma unroll
  for (int i = 0; i < FDIM; i++) efr[i] = loadf(ef, e * FDIM + i, isf32);

  u16x8* hrow = (u16x8*)(hidden + (size_t)e * HID);
  #pragma unroll
  for (int c = 0; c < 4; c++) {
    u16x8 ov;
    #pragma unroll
    for (int j = 0; j < 8; j++) {
      int h = c * 8 + j;
      float acc = b1s[h];
      #pragma unroll
      for (int i = 0; i < FDIM; i++) acc += efr[i] * w1s[i * HID + h];
      ov[j] = f2bf(fmaxf(acc, 0.0f));
    }
    hrow[c] = ov;
  }

  atomicAdd(&deg[d], 1.0f);
  int b = s >> BSH;
  int p = atomicAdd(&cnt[b], 1);
  if (p < CAP) {
    uint2 rec; rec.x = ((uint_t)s << 16) | (uint_t)d; rec.y = (uint_t)e;
    sortbuf[b * CAP + p] = rec;
  } else {
    int op = atomicAdd(ovfcnt, 1);
    if (op < OVCAP) ovf[op] = e;
  }
}

// kernel 2/4: per-edge message — gather 64 B hidden rows, dot2 with Rt, scatter
__global__ void __launch_bounds__(256) k_msg_big(
    const int* __restrict__ src, const int* __restrict__ dst,
    const int* __restrict__ cnt, const int* __restrict__ ovfcnt,
    const int* __restrict__ ovf, const uint2* __restrict__ sortbuf,
    const ushort_t* __restrict__ hidden, const ushort_t* __restrict__ Rt,
    float* __restrict__ agg) {
  __shared__ uint_t hsp[EPB * 20];
  __shared__ int ssrc[EPB], sdst[EPB], seid[EPB];
  int tid = threadIdx.x;
  int t = blockIdx.x;
  if (t < NTILES) {
    int b = t / TPB, ls0 = (t - b * TPB) * EPB;
    int cb = cnt[b]; if (cb > CAP) cb = CAP;
    int nv = cb - ls0; if (nv <= 0) return;
    if (nv > EPB) nv = EPB;
    if (tid < EPB) {
      uint2 rec;
      if (tid < nv) rec = sortbuf[b * CAP + ls0 + tid];
      else { rec.x = 0u; rec.y = 0u; }
      ssrc[tid] = (int)(rec.x >> 16); sdst[tid] = (int)(rec.x & 0xFFFFu);
      seid[tid] = (int)rec.y;
    }
    __syncthreads();
    {
      int row = tid >> 2, chunk = tid & 3;
      uint4 hv = ((const uint4*)(hidden + (size_t)seid[row] * HID))[chunk];
      int base = row * 20 + chunk * 4;
      hsp[base] = hv.x; hsp[base + 1] = hv.y; hsp[base + 2] = hv.z; hsp[base + 3] = hv.w;
    }
    __syncthreads();
    #pragma unroll
    for (int q = 0; q < 4; q++) {
      int item = q * 256 + tid, le = item >> 4, o = item & 15;
      if (le < nv) {
        int s = ssrc[le], d = sdst[le];
        const ushort_t* rrow = Rt + (size_t)s * RT_ROW;
        const uint_t* ru = (const uint_t*)(rrow + o * 32);
        const uint_t* hp = &hsp[le * 20];
        float acc = bf2f(rrow[512 + o]);
        #pragma unroll
        for (int k = 0; k < 16; k++) acc = dot2bf(hp[k], ru[k], acc);
        atomicAdd(&agg[d * NC + o], acc);
      }
    }
  } else {
    int on = *ovfcnt; if (on > OVCAP) on = OVCAP;
    for (int i = (t - NTILES) * 256 + tid; i < on * NC; i += OVB * 256) {
      int e = ovf[i >> 4], o = i & 15;
      int s = src[e], d = dst[e];
      const ushort_t* rrow = Rt + (size_t)s * RT_ROW;
      const uint_t* ru = (const uint_t*)(rrow + o * 32);
      const uint_t* hp = (const uint_t*)(hidden + (size_t)e * HID);
      float acc = bf2f(rrow[512 + o]);
      for (int k = 0; k < 16; k++) acc = dot2bf(hp[k], ru[k], acc);
      atomicAdd(&agg[d * NC + o], acc);
    }
  }
}

// ============ GRU ============
__device__ __forceinline__ void stage_gru(const void* w_ih, const void* w_hh,
                                          const void* b_ih, const void* b_hh,
                                          float* wihT, float* whhT,
                                          float* bih, float* bhh, int isf32, int tid) {
  for (int kk = tid; kk < 3 * NC * NC; kk += 256) {
    int g = kk >> 8, rem = kk & 255, o = rem >> 4, k = rem & 15;
    wihT[g * 272 + k * 17 + o] = loadf(w_ih, kk, isf32);
    whhT[g * 272 + k * 17 + o] = loadf(w_hh, kk, isf32);
  }
  if (tid < 3 * NC) { bih[tid] = loadf(b_ih, tid, isf32); bhh[tid] = loadf(b_hh, tid, isf32); }
}
__device__ __forceinline__ float gru_core(const float* wihT, const float* whhT,
                                          const float* bih, const float* bhh,
                                          const float* x, const float* h, int o) {
  float gir = bih[o], giz = bih[NC + o], gin = bih[2 * NC + o];
  float ghr = bhh[o], ghz = bhh[NC + o], ghn = bhh[2 * NC + o];
  #pragma unroll
  for (int k = 0; k < NC; k++) {
    gir += x[k] * wihT[k * 17 + o];
    giz += x[k] * wihT[272 + k * 17 + o];
    gin += x[k] * wihT[544 + k * 17 + o];
    ghr += h[k] * whhT[k * 17 + o];
    ghz += h[k] * whhT[272 + k * 17 + o];
    ghn += h[k] * whhT[544 + k * 17 + o];
  }
  float r = sigmoidf_(gir + ghr);
  float z = sigmoidf_(giz + ghz);
  float n = tanhf_(gin + r * ghn);
  return (1.0f - z) * n + z * h[o];
}
__device__ __forceinline__ void load_xh(const float* agg, const float* hx, int v,
                                        float inv, float* x, float* h) {
  const float4* ar = (const float4*)(agg + v * NC);
  const float4* hr = (const float4*)(hx + v * NC);
  #pragma unroll
  for (int q = 0; q < 4; q++) {
    float4 aa = ar[q], bb = hr[q];
    x[4 * q + 0] = aa.x * inv; x[4 * q + 1] = aa.y * inv; x[4 * q + 2] = aa.z * inv; x[4 * q + 3] = aa.w * inv;
    h[4 * q + 0] = bb.x; h[4 * q + 1] = bb.y; h[4 * q + 2] = bb.z; h[4 * q + 3] = bb.w;
  }
}

// kernel 3: GRU update (in place) + Rt rebuild + agg re-zero (R10-proven)
__global__ void __launch_bounds__(256) k_update(
    const void* __restrict__ hx_in, const float* __restrict__ agg_in,
    const float* __restrict__ deg, float* __restrict__ hx,
    const void* __restrict__ w_ih, const void* __restrict__ w_hh,
    const void* __restrict__ b_ih, const void* __restrict__ b_hh,
    const void* __restrict__ w2, const void* __restrict__ b2,
    ushort_t* __restrict__ Rt, float* __restrict__ agg_out) {
  __shared__ float w2t[256 * 36];
  __shared__ float b2s[256];
  __shared__ float wihT[816], whhT[816], bih[48], bhh[48];
  __shared__ float hx_l[16 * 17];
  int tid = threadIdx.x;
  int isf32 = detect_f32(hx_in);
  stage_w2(w2, b2, w2t, b2s, isf32);
  stage_gru(w_ih, w_hh, b_ih, b_hh, wihT, whhT, bih, bhh, isf32, tid);
  __syncthreads();

  int idx = blockIdx.x * 256 + tid;
  int v = idx >> 4, o = idx & 15, vl = tid >> 4;
  float inv = 1.0f / fmaxf(deg[v], 1.0f);
  float x[16], h[16];
  load_xh(agg_in, hx, v, inv, x, h);
  float hn = gru_core(wihT, whhT, bih, bhh, x, h, o);
  hx_l[vl * 17 + o] = hn;
  __syncthreads();                 // hx row fully read+staged before in-place write
  hx[idx] = hn;
  agg_out[idx] = 0.0f;

  float hxr[16];
  #pragma unroll
  for (int i = 0; i < 16; i++) hxr[i] = hx_l[vl * 17 + i];
  rt_row(hxr, w2t, b2s, Rt + (size_t)v * RT_ROW, o);
}

// kernel 5: final GRU -> d_out
__global__ void __launch_bounds__(256) k_gru(
    const void* __restrict__ hx_in, const float* __restrict__ agg,
    const float* __restrict__ deg, const float* __restrict__ hx,
    const void* __restrict__ w_ih, const void* __restrict__ w_hh,
    const void* __restrict__ b_ih, const void* __restrict__ b_hh,
    void* __restrict__ out) {
  __shared__ float wihT[816], whhT[816], bih[48], bhh[48];
  int tid = threadIdx.x;
  int isf32 = detect_f32(hx_in);
  stage_gru(w_ih, w_hh, b_ih, b_hh, wihT, whhT, bih, bhh, isf32, tid);
  __syncthreads();
  int idx = blockIdx.x * 256 + tid;
  int v = idx >> 4, o = idx & 15;
  float inv = 1.0f / fmaxf(deg[v], 1.0f);
  float x[16], h[16];
  load_xh(agg, hx, v, inv, x, h);
  float hn = gru_core(wihT, whhT, bih, bhh, x, h, o);
  if (isf32) ((float*)out)[idx] = hn;
  else       ((ushort_t*)out)[idx] = f2bf(hn);
}

// ============ FALLBACK PATH (small ws; R9-proven) ============
__global__ void k_pre9(const void* __restrict__ hx_in, float* __restrict__ hx32,
                       const int* __restrict__ src, const int* __restrict__ dst,
                       float* __restrict__ deg, int* __restrict__ hist) {
  int isf32 = detect_f32(hx_in);
  int idx = blockIdx.x * 256 + threadIdx.x;
  hx32[idx] = loadf(hx_in, idx, isf32);
  atomicAdd(&deg[dst[idx]], 1.0f);
  atomicAdd(&hist[src[idx] >> BSH], 1);
}

__global__ void k_scan_rnode9(const void* __restrict__ hx_in, int* __restrict__ hist,
                              const float* __restrict__ hx, const void* __restrict__ w2,
                              const void* __restrict__ b2, ushort_t* __restrict__ Rt,
                              float* __restrict__ agg) {
  __shared__ int lds[NBUCK9];
  __shared__ int psum[256];
  __shared__ float w2t[256 * 36];
  __shared__ float b2s[256];
  int tid = threadIdx.x;
  if (blockIdx.x == 0) {
    for (int i = tid; i < NBUCK9; i += 256) lds[i] = hist[i];
    __syncthreads();
    int base = tid * 25, s = 0;
    #pragma unroll
    for (int i = 0; i < 25; i++) { int v = lds[base + i]; lds[base + i] = s; s += v; }
    psum[tid] = s;
    __syncthreads();
    if (tid == 0) { int run = 0; for (int i = 0; i < 256; i++) { int v = psum[i]; psum[i] = run; run += v; } }
    __syncthreads();
    int off = psum[tid];
    #pragma unroll
    for (int i = 0; i < 25; i++) lds[base + i] += off;
    __syncthreads();
    for (int i = tid; i < NBUCK9; i += 256) hist[i] = lds[i];
    return;
  }
  int isf32 = detect_f32(hx_in);
  stage_w2(w2, b2, w2t, b2s, isf32);
  __syncthreads();
  int idx = (blockIdx.x - 1) * 256 + tid;
  agg[idx] = 0.0f;
  int node = idx >> 4, o = idx & 15;
  float hxr[16];
  const float4* hp = (const float4*)(hx + node * NC);
  #pragma unroll
  for (int q = 0; q < 4; q++) {
    float4 t = hp[q];
    hxr[4 * q + 0] = t.x; hxr[4 * q + 1] = t.y; hxr[4 * q + 2] = t.z; hxr[4 * q + 3] = t.w;
  }
  rt_row(hxr, w2t, b2s, Rt + (size_t)node * RT_ROW, o);
}

__global__ void k_scatter9(const int* __restrict__ src, const int* __restrict__ dst,
                           int* __restrict__ cursors, uint2* __restrict__ sortbuf) {
  int e = blockIdx.x * 256 + threadIdx.x;
  int s = src[e];
  int p = atomicAdd(&cursors[s >> BSH], 1);
  uint2 rec; rec.x = ((uint_t)s << 16) | (uint_t)dst[e]; rec.y = (uint_t)e;
  sortbuf[p] = rec;
}

__global__ void __launch_bounds__(256) k_msg9(
    const void* __restrict__ hx_in, const uint2* __restrict__ sortbuf,
    const void* __restrict__ ef, const void* __restrict__ w1,
    const void* __restrict__ b1, const ushort_t* __restrict__ Rt,
    float* __restrict__ agg) {
  __shared__ float w1s[FDIM * HID];
  __shared__ float b1s[HID];
  __shared__ float efs[EPB * FDIM];
  __shared__ uint_t hsp[EPB * 20];
  __shared__ int ssrc[EPB], sdst[EPB], seid[EPB];
  int tid = threadIdx.x;
  int isf32 = detect_f32(hx_in);
  int e0 = blockIdx.x * EPB;
  for (int k = tid; k < FDIM * HID; k += 256) w1s[k] = loadf(w1, k, isf32);
  if (tid < HID) b1s[tid] = loadf(b1, tid, isf32);
  if (tid < EPB) {
    uint2 rec = sortbuf[e0 + tid];
    ssrc[tid] = (int)(rec.x >> 16); sdst[tid] = (int)(rec.x & 0xFFFFu);
    seid[tid] = (int)rec.y;
  }
  __syncthreads();
  #pragma unroll
  for (int q = 0; q < 4; q++) {
    int j = q * 256 + tid, le = j >> 4, i = j & 15;
    if (i < FDIM) efs[le * FDIM + i] = loadf(ef, seid[le] * FDIM + i, isf32);
  }
  __syncthreads();
  #pragma unroll
  for (int q = 0; q < 4; q++) {
    int v = q * 256 + tid;
    int le = v >> 4, hp2 = v & 15, h0 = hp2 * 2;
    float a0 = b1s[h0], a1 = b1s[h0 + 1];
    #pragma unroll
    for (int i = 0; i < FDIM; i++) {
      float e = efs[le * FDIM + i];
      a0 += e * w1s[i * HID + h0];
      a1 += e * w1s[i * HID + h0 + 1];
    }
    hsp[le * 20 + hp2] = (uint_t)f2bf(fmaxf(a0, 0.0f)) | ((uint_t)f2bf(fmaxf(a1, 0.0f)) << 16);
  }
  __syncthreads();
  #pragma unroll
  for (int q = 0; q < 4; q++) {
    int item = q * 256 + tid, le = item >> 4, o = item & 15;
    int s = ssrc[le], d = sdst[le];
    const ushort_t* rrow = Rt + (size_t)s * RT_ROW;
    const uint_t* ru = (const uint_t*)(rrow + o * 32);
    const uint_t* hp = &hsp[le * 20];
    float acc = bf2f(rrow[512 + o]);
    #pragma unroll
    for (int k = 0; k < 16; k++) acc = dot2bf(hp[k], ru[k], acc);
    atomicAdd(&agg[d * NC + o], acc);
  }
}

extern "C" void kernel_launch(void* const* d_in, const int* in_sizes, int n_in,
                              void* d_out, int out_size, void* d_ws, size_t ws_size,
                              hipStream_t stream) {
  const void* hx_in = d_in[0];
  const void* ef    = d_in[1];
  const int*  esrc  = (const int*)d_in[2];
  const int*  edst  = (const int*)d_in[3];
  const void* w1    = d_in[4];
  const void* b1    = d_in[5];
  const void* w2    = d_in[6];
  const void* b2    = d_in[7];
  const void* wih   = d_in[8];
  const void* whh   = d_in[9];
  const void* bih_g = d_in[10];
  const void* bhh_g = d_in[11];

  char* ws = (char*)d_ws;
  float* hx32   = (float*)(ws + 0);          //  3,200,000
  float* agg    = (float*)(ws + 3200000);    //  3,200,000
  float* deg    = (float*)(ws + 6400000);    //    200,000  -- zero region start
  int*   cnt    = (int*)  (ws + 6600000);    //     25,600
  int*   ovfcnt = (int*)  (ws + 6625600);    //         32  -- zero region end
  int*   ovf    = (int*)  (ws + 6625632);    //     16,384
  uint2*    sortbufB = (uint2*)(ws + 6642016);       //  9,600,000
  ushort_t* hiddenB  = (ushort_t*)(ws + 16242016);   // 51,200,000
  ushort_t* RtB      = (ushort_t*)(ws + 67442016);   // 52,800,000 -> 120,242,016
  uint2*    sortbuf9 = (uint2*)(ws + 6642016);       //  6,400,000
  ushort_t* Rt9      = (ushort_t*)(ws + 13042016);   // 52,800,000 -> 65,842,016

  int big = (ws_size >= (size_t)120242016);
  hipMemsetAsync(ws + 6400000, 0, 225632, stream);   // deg + cnt + ovfcnt

  if (big) {
    k_node<<<3125, 256, 0, stream>>>(hx_in, w2, b2, hx32, agg, RtB);
    k_edge_pre<<<3125, 256, 0, stream>>>(hx_in, ef, esrc, edst, w1, b1,
                                         deg, cnt, ovfcnt, ovf, sortbufB, hiddenB);
    k_msg_big<<<NTILES + OVB, 256, 0, stream>>>(esrc, edst, cnt, ovfcnt, ovf,
                                                sortbufB, hiddenB, RtB, agg);
    k_update<<<3125, 256, 0, stream>>>(hx_in, agg, deg, hx32, wih, whh, bih_g, bhh_g,
                                       w2, b2, RtB, agg);
    k_msg_big<<<NTILES + OVB, 256, 0, stream>>>(esrc, edst, cnt, ovfcnt, ovf,
                                                sortbufB, hiddenB, RtB, agg);
    k_gru<<<3125, 256, 0, stream>>>(hx_in, agg, deg, hx32, wih, whh, bih_g, bhh_g, d_out);
  } else {
    k_pre9<<<3125, 256, 0, stream>>>(hx_in, hx32, esrc, edst, deg, cnt);
    k_scan_rnode9<<<3126, 256, 0, stream>>>(hx_in, cnt, hx32, w2, b2, Rt9, agg);
    k_scatter9<<<3125, 256, 0, stream>>>(esrc, edst, cnt, sortbuf9);
    k_msg9<<<MTILE, 256, 0, stream>>>(hx_in, sortbuf9, ef, w1, b1, Rt9, agg);
    k_update<<<3125, 256, 0, stream>>>(hx_in, agg, deg, hx32, wih, whh, bih_g, bhh_g,
                                       w2, b2, Rt9, agg);
    k_msg9<<<MTILE, 256, 0, stream>>>(hx_in, sortbuf9, ef, w1, b1, Rt9, agg);
    k_gru<<<3125, 256, 0, stream>>>(hx_in, agg, deg, hx32, wih, whh, bih_g, bhh_g, d_out);
  }
}